// Round 1
// baseline (560.657 us; speedup 1.0000x reference)
//
#include <hip/hip_runtime.h>
#include <hip/hip_fp16.h>
#include <math.h>

// CrossFeatureAffinityPooling on gfx950
// Pipeline: k_convert (fp32->fp16 U, W) -> k_qkgemm (MFMA, q^T/k^T fp16 [b][n][c])
//        -> k_attn (flash-style fused QK^T/softmax/PV, fp16 MFMA, fp32 online stats)
//        -> k_gnstats -> k_gnapply (groupnorm + residual, LDS transpose for coalesced out)

typedef _Float16 v8h __attribute__((ext_vector_type(8)));
typedef float    v4f __attribute__((ext_vector_type(4)));

#define NB 4
#define NC 256
#define NS 4096
#define NG 32
#define GEPS 1e-5f

// ---------------- K0: convert U and weight matrices to fp16 ----------------
__global__ __launch_bounds__(256) void k_convert(const float* __restrict__ U,
    const float* __restrict__ Wh, const float* __restrict__ Wu,
    _Float16* __restrict__ Uh, _Float16* __restrict__ Wh16, _Float16* __restrict__ Wu16)
{
    const int i = blockIdx.x * 256 + threadIdx.x;   // grid sized exactly NB*NC*NS
    Uh[i] = (_Float16)U[i];
    if (i < NC * NC) { Wh16[i] = (_Float16)Wh[i]; Wu16[i] = (_Float16)Wu[i]; }
}

// ---------------- K1: q^T = (WH x Hand)^T + b ; k^T = (WU x U)^T + b -------
// Output layout [b][n][c] fp16 so attention A/B frags are contiguous.
// D[row=n][col=o] = sum_c X^T[n][c] * W^T[c][o];  A-frag: row=lane&15, k=quad*8+j
__global__ __launch_bounds__(256) void k_qkgemm(const float* __restrict__ Hand,
    const float* __restrict__ U, const _Float16* __restrict__ Wh16,
    const _Float16* __restrict__ Wu16, const float* __restrict__ WHb,
    const float* __restrict__ WUb, _Float16* __restrict__ qT, _Float16* __restrict__ kT)
{
    const int nt = blockIdx.x, b = blockIdx.y, z = blockIdx.z;
    const float*    X    = z ? U    : Hand;
    const _Float16* W    = z ? Wu16 : Wh16;
    const float*    bias = z ? WUb  : WHb;
    _Float16*       out  = z ? kT   : qT;

    const int tid = threadIdx.x, w = tid >> 6, lane = tid & 63;
    const int q4 = lane >> 4, l15 = lane & 15;
    const int n = nt * 64 + w * 16 + l15;

    // A-frags: X^T[n][c], strided gather from X[b][c][n] + cvt fp16 (read once, reuse x16)
    const float* Xcol = X + (size_t)b * NC * NS + n;
    v8h A[8];
#pragma unroll
    for (int kc = 0; kc < 8; ++kc) {
        const int c0 = kc * 32 + q4 * 8;
        v8h a;
#pragma unroll
        for (int j = 0; j < 8; ++j) a[j] = (_Float16)Xcol[(size_t)(c0 + j) * NS];
        A[kc] = a;
    }

#pragma unroll 4
    for (int osub = 0; osub < 16; ++osub) {
        const int o = osub * 16 + l15;
        const _Float16* Wrow = W + (size_t)o * NC;     // W[o][c], contiguous c
        v4f acc = {0.f, 0.f, 0.f, 0.f};
#pragma unroll
        for (int kc = 0; kc < 8; ++kc) {
            const v8h bf = *(const v8h*)(Wrow + kc * 32 + q4 * 8);
            acc = __builtin_amdgcn_mfma_f32_16x16x32_f16(A[kc], bf, acc, 0, 0, 0);
        }
        const float bv = bias[o];
        _Float16* orow = out + ((size_t)b * NS + nt * 64 + w * 16 + q4 * 4) * NC + o;
#pragma unroll
        for (int r = 0; r < 4; ++r) orow[(size_t)r * NC] = (_Float16)(acc[r] + bv);
    }
}

// ---------------- K2: fused affinity + softmax + pooling -------------------
// Block = (batch b, 64-row n-tile), 256 threads = 4 waves.
// QK phase: wave w owns S rows [w*16, w*16+16) x 64 m.
// PV phase: wave w owns O cols c in [w*64, w*64+64) x all 64 n.
// K/U frags are use-once -> direct global (L2) loads. P goes via swizzled LDS.
__global__ __launch_bounds__(256) void k_attn(const _Float16* __restrict__ qT,
    const _Float16* __restrict__ kT, const _Float16* __restrict__ Uh,
    float* __restrict__ Opre)
{
    const int b  = blockIdx.x;   // batch fastest -> id%8 XCD round-robin pins batch/XCD
    const int nt = blockIdx.y;

    __shared__ _Float16 Plds[64 * 64];   // rows n (64), 64 m halves, XOR-16B-swizzled
    __shared__ float alphaS[64];
    __shared__ float lS[64];

    const int tid = threadIdx.x, w = tid >> 6, lane = tid & 63;
    const int q4 = lane >> 4, l15 = lane & 15;

    // persistent Q frags: q^T[n][c], n = nt*64 + w*16 + l15
    v8h Q[8];
    {
        const _Float16* qrow = qT + ((size_t)b * NS + nt * 64 + w * 16 + l15) * NC;
#pragma unroll
        for (int kc = 0; kc < 8; ++kc) Q[kc] = *(const v8h*)(qrow + kc * 32 + q4 * 8);
    }

    v4f O[4][4];
#pragma unroll
    for (int i = 0; i < 4; ++i)
#pragma unroll
        for (int j = 0; j < 4; ++j) O[i][j] = (v4f){0.f, 0.f, 0.f, 0.f};

    float mi[4] = {-INFINITY, -INFINITY, -INFINITY, -INFINITY};
    float li[4] = {0.f, 0.f, 0.f, 0.f};

    const _Float16* kTb = kT + (size_t)b * NS * NC;  // [m][c]
    const _Float16* Uhb = Uh + (size_t)b * NC * NS;  // [c][m]

    for (int m0 = 0; m0 < NS; m0 += 64) {
        // ---- QK^T: S[16 n x 64 m] per wave; B-frag = k^T[m][c] direct from L2 ----
        v4f s[4];
#pragma unroll
        for (int ms = 0; ms < 4; ++ms) s[ms] = (v4f){0.f, 0.f, 0.f, 0.f};
#pragma unroll
        for (int kc = 0; kc < 8; ++kc) {
#pragma unroll
            for (int ms = 0; ms < 4; ++ms) {
                const v8h kf = *(const v8h*)(kTb + (size_t)(m0 + ms * 16 + l15) * NC
                                             + kc * 32 + q4 * 8);
                s[ms] = __builtin_amdgcn_mfma_f32_16x16x32_f16(Q[kc], kf, s[ms], 0, 0, 0);
            }
        }

        // ---- online softmax; lane holds rows (q4*4+r), cols ms*16+l15 ----
        float al[4];
#pragma unroll
        for (int r = 0; r < 4; ++r) {
            float tm = fmaxf(fmaxf(s[0][r], s[1][r]), fmaxf(s[2][r], s[3][r]));
#pragma unroll
            for (int off = 1; off < 16; off <<= 1) tm = fmaxf(tm, __shfl_xor(tm, off, 64));
            const float mn = fmaxf(mi[r], tm);         // tm finite -> no NaN from -inf
            al[r] = __expf(mi[r] - mn);
            mi[r] = mn;
            float sum = 0.f;
#pragma unroll
            for (int ms = 0; ms < 4; ++ms) {
                const float p = __expf(s[ms][r] - mn);
                s[ms][r] = p; sum += p;
            }
#pragma unroll
            for (int off = 1; off < 16; off <<= 1) sum += __shfl_xor(sum, off, 64);
            li[r] = li[r] * al[r] + sum;
        }
        if (l15 == 0) {
#pragma unroll
            for (int r = 0; r < 4; ++r) alphaS[w * 16 + q4 * 4 + r] = al[r];
        }
        // P -> LDS in fp16, 16B-chunk XOR swizzle: phys_chunk = (col>>3) ^ (row&7)
#pragma unroll
        for (int ms = 0; ms < 4; ++ms)
#pragma unroll
            for (int r = 0; r < 4; ++r) {
                const int row = w * 16 + q4 * 4 + r;
                const int col = ms * 16 + l15;
                Plds[row * 64 + (((col >> 3) ^ (row & 7)) * 8) + (col & 7)] = (_Float16)s[ms][r];
            }
        __syncthreads();

        // ---- rescale O by alpha, then O += P * V (V = Uh[c][m], native layout) ----
#pragma unroll
        for (int is = 0; is < 4; ++is) {
            v4f aa;
#pragma unroll
            for (int r = 0; r < 4; ++r) aa[r] = alphaS[is * 16 + q4 * 4 + r];
#pragma unroll
            for (int js = 0; js < 4; ++js) O[is][js] *= aa;
        }
#pragma unroll
        for (int mc = 0; mc < 2; ++mc) {
            v8h Pf[4];
#pragma unroll
            for (int is = 0; is < 4; ++is) {
                const int row = is * 16 + l15;
                const int ch = mc * 4 + q4;
                Pf[is] = *(const v8h*)(Plds + row * 64 + ((ch ^ (row & 7)) * 8));
            }
#pragma unroll
            for (int js = 0; js < 4; ++js) {
                const v8h Uf = *(const v8h*)(Uhb + (size_t)(w * 64 + js * 16 + l15) * NS
                                             + m0 + mc * 32 + q4 * 8);
#pragma unroll
                for (int is = 0; is < 4; ++is)
                    O[is][js] = __builtin_amdgcn_mfma_f32_16x16x32_f16(Pf[is], Uf, O[is][js], 0, 0, 0);
            }
        }
        __syncthreads();   // protect Plds/alphaS for next iteration
    }

    // ---- epilogue: normalize by l and write Opre[b][n][c] fp32 ----
    if (l15 == 0) {
#pragma unroll
        for (int r = 0; r < 4; ++r) lS[w * 16 + q4 * 4 + r] = li[r];
    }
    __syncthreads();
#pragma unroll
    for (int is = 0; is < 4; ++is) {
        v4f linv;
#pragma unroll
        for (int r = 0; r < 4; ++r) linv[r] = 1.f / lS[is * 16 + q4 * 4 + r];
#pragma unroll
        for (int js = 0; js < 4; ++js) {
#pragma unroll
            for (int r = 0; r < 4; ++r) {
                Opre[((size_t)b * NS + nt * 64 + is * 16 + q4 * 4 + r) * NC
                     + w * 64 + js * 16 + l15] = O[is][js][r] * linv[r];
            }
        }
    }
}

// ---------------- K3: groupnorm stats (mean, rstd) per (b, group) ----------
__global__ __launch_bounds__(256) void k_gnstats(const float* __restrict__ Opre,
                                                 float* __restrict__ stats)
{
    const int b = blockIdx.x, g = blockIdx.y;
    const int tid = threadIdx.x;
    const int coff = tid & 7, nb0 = tid >> 3;
    const float* base = Opre + (size_t)b * NS * NC + g * 8 + coff;
    float sum = 0.f, ss = 0.f;
#pragma unroll 4
    for (int k = 0; k < 128; ++k) {
        const float v = base[(size_t)(nb0 + 32 * k) * NC];
        sum += v; ss += v * v;
    }
    __shared__ float r1[256], r2[256];
    r1[tid] = sum; r2[tid] = ss;
    __syncthreads();
    for (int sft = 128; sft > 0; sft >>= 1) {
        if (tid < sft) { r1[tid] += r1[tid + sft]; r2[tid] += r2[tid + sft]; }
        __syncthreads();
    }
    if (tid == 0) {
        const float mean = r1[0] * (1.f / 32768.f);
        const float var  = r2[0] * (1.f / 32768.f) - mean * mean;
        stats[(b * NG + g) * 2 + 0] = mean;
        stats[(b * NG + g) * 2 + 1] = rsqrtf(var + GEPS);
    }
}

// ---------------- K4: apply GN + residual, transpose [b][n][c]->[b][c][n] --
__global__ __launch_bounds__(256) void k_gnapply(const float* __restrict__ Opre,
    const float* __restrict__ Hand, const float* __restrict__ gnw,
    const float* __restrict__ gnb, const float* __restrict__ stats,
    float* __restrict__ out)
{
    const int nt = blockIdx.x, ct = blockIdx.y, b = blockIdx.z;
    __shared__ float buf[64 * 65];                 // +1 pad: conflict-free transpose
    const int tid = threadIdx.x;
    {
        const int nr = tid >> 4, c4 = (tid & 15) * 4;
#pragma unroll
        for (int k = 0; k < 4; ++k) {
            const int n = nr + 16 * k;
            const float4 v = *(const float4*)(Opre + ((size_t)b * NS + nt * 64 + n) * NC
                                              + ct * 64 + c4);
            buf[n * 65 + c4 + 0] = v.x; buf[n * 65 + c4 + 1] = v.y;
            buf[n * 65 + c4 + 2] = v.z; buf[n * 65 + c4 + 3] = v.w;
        }
    }
    __syncthreads();
    const int nw = tid & 63, c0 = tid >> 6;
#pragma unroll
    for (int k = 0; k < 16; ++k) {
        const int cl = c0 + 4 * k;
        const int c  = ct * 64 + cl;
        const int g  = c >> 3;
        const float mean = stats[(b * NG + g) * 2 + 0];
        const float rstd = stats[(b * NG + g) * 2 + 1];
        const size_t oidx = ((size_t)b * NC + c) * NS + nt * 64 + nw;
        out[oidx] = (buf[nw * 65 + cl] - mean) * rstd * gnw[c] + gnb[c] + Hand[oidx];
    }
}

extern "C" void kernel_launch(void* const* d_in, const int* in_sizes, int n_in,
                              void* d_out, int out_size, void* d_ws, size_t ws_size,
                              hipStream_t stream)
{
    const float* Hand = (const float*)d_in[0];
    const float* U    = (const float*)d_in[1];
    const float* WHw  = (const float*)d_in[2];
    const float* WHb  = (const float*)d_in[3];
    const float* WUw  = (const float*)d_in[4];
    const float* WUb  = (const float*)d_in[5];
    const float* gnw  = (const float*)d_in[6];
    const float* gnb  = (const float*)d_in[7];
    float* out = (float*)d_out;

    // workspace carve-up (~40.3 MiB total)
    char* ws = (char*)d_ws;
    _Float16* qT   = (_Float16*)(ws);                       //  8 MiB  [b][n][c]
    _Float16* kT   = (_Float16*)(ws + 8388608);             //  8 MiB  [b][m][c]
    _Float16* Uh   = (_Float16*)(ws + 16777216);            //  8 MiB  [b][c][m]
    _Float16* Wh16 = (_Float16*)(ws + 25165824);            //  128 KiB
    _Float16* Wu16 = (_Float16*)(ws + 25296896);            //  128 KiB
    float*    Opre = (float*)(ws + 25427968);               //  16 MiB [b][n][c]
    float*    stats= (float*)(ws + 42205184);               //  1 KiB

    k_convert<<<dim3((NB * NC * NS) / 256), 256, 0, stream>>>(U, WHw, WUw, Uh, Wh16, Wu16);
    k_qkgemm <<<dim3(64, NB, 2), 256, 0, stream>>>(Hand, U, Wh16, Wu16, WHb, WUb, qT, kT);
    k_attn   <<<dim3(NB, 64),    256, 0, stream>>>(qT, kT, Uh, Opre);
    k_gnstats<<<dim3(NB, NG),    256, 0, stream>>>(Opre, stats);
    k_gnapply<<<dim3(64, 4, NB), 256, 0, stream>>>(Opre, Hand, gnw, gnb, stats, out);
}

// Round 2
// 435.263 us; speedup vs baseline: 1.2881x; 1.2881x over previous
//
#include <hip/hip_runtime.h>
#include <hip/hip_fp16.h>
#include <math.h>

// CrossFeatureAffinityPooling on gfx950 — R2
// k_convert -> k_qkgemm (qT linear [b][n][c]; kT pre-SWIZZLED 64x256 tiles for DMA)
// -> k_attn (flash, m-split S=3, K-tile via global_load_lds, fp16 partials + m/l)
// -> k_merge (flash-decoding combine -> fp32 Opre, aliases dead qT/kTsw)
// -> k_gnstats -> k_gnapply

typedef _Float16 v8h __attribute__((ext_vector_type(8)));
typedef float    v4f __attribute__((ext_vector_type(4)));

#define NB 4
#define NC 256
#define NS 4096
#define NG 32
#define GEPS 1e-5f
#define NSPLIT 3

// swizzled kT tile: tile (b, mt) is 64 rows x 256 c, halfword offset within tile:
//   m*256 + (((c>>3) ^ (m&7)) * 8) + (c&7)
// -> global_load_lds identity-copies the tile; ds_read_b128 is 2-way (free).

// ---------------- K0: convert U and weights to fp16 ----------------
__global__ __launch_bounds__(256) void k_convert(const float* __restrict__ U,
    const float* __restrict__ Wh, const float* __restrict__ Wu,
    _Float16* __restrict__ Uh, _Float16* __restrict__ Wh16, _Float16* __restrict__ Wu16)
{
    const int i = blockIdx.x * 256 + threadIdx.x;
    Uh[i] = (_Float16)U[i];
    if (i < NC * NC) { Wh16[i] = (_Float16)Wh[i]; Wu16[i] = (_Float16)Wu[i]; }
}

// ---------------- K1: q^T / k^T GEMM ----------------
__global__ __launch_bounds__(256) void k_qkgemm(const float* __restrict__ Hand,
    const float* __restrict__ U, const _Float16* __restrict__ Wh16,
    const _Float16* __restrict__ Wu16, const float* __restrict__ WHb,
    const float* __restrict__ WUb, _Float16* __restrict__ qT, _Float16* __restrict__ kTsw)
{
    const int nt = blockIdx.x, b = blockIdx.y, z = blockIdx.z;
    const float*    X    = z ? U    : Hand;
    const _Float16* W    = z ? Wu16 : Wh16;
    const float*    bias = z ? WUb  : WHb;

    const int tid = threadIdx.x, w = tid >> 6, lane = tid & 63;
    const int q4 = lane >> 4, l15 = lane & 15;
    const int n = nt * 64 + w * 16 + l15;

    // A-frags: X^T[n][c] strided gather (coalesced across lanes), cvt fp16
    const float* Xcol = X + (size_t)b * NC * NS + n;
    v8h A[8];
#pragma unroll
    for (int kc = 0; kc < 8; ++kc) {
        const int c0 = kc * 32 + q4 * 8;
        v8h a;
#pragma unroll
        for (int j = 0; j < 8; ++j) a[j] = (_Float16)Xcol[(size_t)(c0 + j) * NS];
        A[kc] = a;
    }

#pragma unroll 4
    for (int osub = 0; osub < 16; ++osub) {
        const int o = osub * 16 + l15;
        const _Float16* Wrow = W + (size_t)o * NC;
        v4f acc = {0.f, 0.f, 0.f, 0.f};
#pragma unroll
        for (int kc = 0; kc < 8; ++kc) {
            const v8h bf = *(const v8h*)(Wrow + kc * 32 + q4 * 8);
            acc = __builtin_amdgcn_mfma_f32_16x16x32_f16(A[kc], bf, acc, 0, 0, 0);
        }
        const float bv = bias[o];
        if (z == 0) {
            _Float16* orow = qT + ((size_t)b * NS + nt * 64 + w * 16 + q4 * 4) * NC + o;
#pragma unroll
            for (int r = 0; r < 4; ++r) orow[(size_t)r * NC] = (_Float16)(acc[r] + bv);
        } else {
            _Float16* tile = kTsw + (size_t)(b * 64 + nt) * 16384;
#pragma unroll
            for (int r = 0; r < 4; ++r) {
                const int m = w * 16 + q4 * 4 + r;
                tile[m * 256 + (((o >> 3) ^ (m & 7)) * 8) + (o & 7)] = (_Float16)(acc[r] + bv);
            }
        }
    }
}

// ---------------- K2: flash attention partial (m-split) ----------------
// Block (b, nt, s): 64 n-rows x m-tiles [t0,t1). 256 thr / 4 waves.
// K-tile: swizzled global -> LDS via global_load_lds (identity copy), single
// buffer; DMA for t+1 issued after the P-ready barrier (K reads complete).
__global__ __launch_bounds__(256, 3) void k_attn(const _Float16* __restrict__ qT,
    const _Float16* __restrict__ kTsw, const _Float16* __restrict__ Uh,
    _Float16* __restrict__ Ppart, float* __restrict__ mstat, float* __restrict__ lstat)
{
    const int b  = blockIdx.x;     // fastest -> XCD gets a single batch's K/U set
    const int nt = blockIdx.y;
    const int s  = blockIdx.z;
    const int t0 = (s == 0) ? 0 : 22 + (s - 1) * 21;
    const int t1 = t0 + ((s == 0) ? 22 : 21);

    __shared__ __align__(16) _Float16 Klds[64 * 256];   // 32 KB swizzled K tile
    __shared__ __align__(16) _Float16 Plds[64 * 64];    // 8 KB swizzled P
    __shared__ float alphaS[64];

    const int tid = threadIdx.x, w = tid >> 6, lane = tid & 63;
    const int q4 = lane >> 4, l15 = lane & 15;

    const _Float16* kTb = kTsw + (size_t)b * 64 * 16384;
    const _Float16* Uhb = Uh + (size_t)b * NC * NS;

    // stage K tile t0 (each wave DMAs 8 KB = 8 chunks of 1 KB)
    {
        const _Float16* src = kTb + (size_t)t0 * 16384;
#pragma unroll
        for (int j = 0; j < 8; ++j) {
            const int ch = w * 8 + j;
            __builtin_amdgcn_global_load_lds(
                (const __attribute__((address_space(1))) void*)(src + ch * 512 + lane * 8),
                (__attribute__((address_space(3))) void*)(Klds + ch * 512), 16, 0, 0);
        }
    }

    // persistent Q frags
    v8h Q[8];
    {
        const _Float16* qrow = qT + ((size_t)b * NS + nt * 64 + w * 16 + l15) * NC;
#pragma unroll
        for (int kc = 0; kc < 8; ++kc) Q[kc] = *(const v8h*)(qrow + kc * 32 + q4 * 8);
    }

    v4f O[4][4];
#pragma unroll
    for (int i = 0; i < 4; ++i)
#pragma unroll
        for (int j = 0; j < 4; ++j) O[i][j] = (v4f){0.f, 0.f, 0.f, 0.f};
    float mi[4] = {-INFINITY, -INFINITY, -INFINITY, -INFINITY};
    float li[4] = {0.f, 0.f, 0.f, 0.f};

    for (int t = t0; t < t1; ++t) {
        const int m0 = t * 64;
        __builtin_amdgcn_s_waitcnt(0);   // DMA (and own loads) drained
        __syncthreads();                 // K[t] visible to all; Plds consumed

        // ---- QK^T: S[16 n x 64 m] per wave, B-frags from swizzled Klds ----
        v4f sv[4];
#pragma unroll
        for (int ms = 0; ms < 4; ++ms) sv[ms] = (v4f){0.f, 0.f, 0.f, 0.f};
#pragma unroll
        for (int kc = 0; kc < 8; ++kc) {
#pragma unroll
            for (int ms = 0; ms < 4; ++ms) {
                const v8h kf = *(const v8h*)(Klds + (ms * 16 + l15) * 256
                                             + (((kc * 4 + q4) ^ (l15 & 7)) * 8));
                sv[ms] = __builtin_amdgcn_mfma_f32_16x16x32_f16(Q[kc], kf, sv[ms], 0, 0, 0);
            }
        }

        // ---- online softmax (rows q4*4+r per lane-quad) ----
        float al[4];
#pragma unroll
        for (int r = 0; r < 4; ++r) {
            float tm = fmaxf(fmaxf(sv[0][r], sv[1][r]), fmaxf(sv[2][r], sv[3][r]));
#pragma unroll
            for (int off = 1; off < 16; off <<= 1) tm = fmaxf(tm, __shfl_xor(tm, off, 64));
            const float mn = fmaxf(mi[r], tm);
            al[r] = __expf(mi[r] - mn);
            mi[r] = mn;
            float sum = 0.f;
#pragma unroll
            for (int ms = 0; ms < 4; ++ms) {
                const float p = __expf(sv[ms][r] - mn);
                sv[ms][r] = p; sum += p;
            }
#pragma unroll
            for (int off = 1; off < 16; off <<= 1) sum += __shfl_xor(sum, off, 64);
            li[r] = li[r] * al[r] + sum;
        }
        if (l15 == 0) {
#pragma unroll
            for (int r = 0; r < 4; ++r) alphaS[w * 16 + q4 * 4 + r] = al[r];
        }
        // P -> LDS fp16, 16B-chunk XOR swizzle
#pragma unroll
        for (int ms = 0; ms < 4; ++ms)
#pragma unroll
            for (int r = 0; r < 4; ++r) {
                const int row = w * 16 + q4 * 4 + r;
                const int col = ms * 16 + l15;
                Plds[row * 64 + (((col >> 3) ^ (row & 7)) * 8) + (col & 7)] = (_Float16)sv[ms][r];
            }
        __syncthreads();                 // P/alpha ready; all K[t] reads done

        // stage K[t+1] — overwrites Klds, safe after the barrier above
        if (t + 1 < t1) {
            const _Float16* src = kTb + (size_t)(t + 1) * 16384;
#pragma unroll
            for (int j = 0; j < 8; ++j) {
                const int ch = w * 8 + j;
                __builtin_amdgcn_global_load_lds(
                    (const __attribute__((address_space(1))) void*)(src + ch * 512 + lane * 8),
                    (__attribute__((address_space(3))) void*)(Klds + ch * 512), 16, 0, 0);
            }
        }

        // ---- O = O*alpha + P x V ----
#pragma unroll
        for (int is = 0; is < 4; ++is) {
            v4f aa;
#pragma unroll
            for (int r = 0; r < 4; ++r) aa[r] = alphaS[is * 16 + q4 * 4 + r];
#pragma unroll
            for (int js = 0; js < 4; ++js) O[is][js] *= aa;
        }
#pragma unroll
        for (int mc = 0; mc < 2; ++mc) {
            v8h Pf[4];
#pragma unroll
            for (int is = 0; is < 4; ++is) {
                const int row = is * 16 + l15;
                const int ch = mc * 4 + q4;
                Pf[is] = *(const v8h*)(Plds + row * 64 + ((ch ^ (row & 7)) * 8));
            }
#pragma unroll
            for (int js = 0; js < 4; ++js) {
                const v8h Uf = *(const v8h*)(Uhb + (size_t)(w * 64 + js * 16 + l15) * NS
                                             + m0 + mc * 32 + q4 * 8);
#pragma unroll
                for (int is = 0; is < 4; ++is)
                    O[is][js] = __builtin_amdgcn_mfma_f32_16x16x32_f16(Pf[is], Uf, O[is][js], 0, 0, 0);
            }
        }
    }

    // ---- epilogue: raw partial O (fp16) + per-row m,l ----
    if (l15 == 0) {
#pragma unroll
        for (int r = 0; r < 4; ++r) {
            const int n = nt * 64 + w * 16 + q4 * 4 + r;
            mstat[(size_t)(s * NB + b) * NS + n] = mi[r];
            lstat[(size_t)(s * NB + b) * NS + n] = li[r];
        }
    }
#pragma unroll
    for (int is = 0; is < 4; ++is)
#pragma unroll
        for (int js = 0; js < 4; ++js)
#pragma unroll
            for (int r = 0; r < 4; ++r) {
                Ppart[((size_t)(s * NB + b) * NS + nt * 64 + is * 16 + q4 * 4 + r) * NC
                      + w * 64 + js * 16 + l15] = (_Float16)O[is][js][r];
            }
}

// ---------------- K3: flash-decoding merge of 3 partials -> fp32 Opre ------
__global__ __launch_bounds__(256) void k_merge(const _Float16* __restrict__ Pp,
    const float* __restrict__ mstat, const float* __restrict__ lstat,
    float* __restrict__ Opre)
{
    const int b = blockIdx.y, tid = threadIdx.x;
    const int n = blockIdx.x * 8 + (tid >> 5);
    const int c0 = (tid & 31) * 8;
    const size_t nb = (size_t)b * NS + n;
    const size_t SP = (size_t)NB * NS;
    const float m0 = mstat[nb], m1 = mstat[SP + nb], m2 = mstat[2 * SP + nb];
    const float l0 = lstat[nb], l1 = lstat[SP + nb], l2 = lstat[2 * SP + nb];
    const float M  = fmaxf(m0, fmaxf(m1, m2));
    const float e0 = __expf(m0 - M), e1 = __expf(m1 - M), e2 = __expf(m2 - M);
    const float inv = 1.f / (e0 * l0 + e1 * l1 + e2 * l2);
    const float w0 = e0 * inv, w1 = e1 * inv, w2 = e2 * inv;
    const size_t base = nb * NC + c0;
    const v8h p0 = *(const v8h*)(Pp + base);
    const v8h p1 = *(const v8h*)(Pp + SP * NC + base);
    const v8h p2 = *(const v8h*)(Pp + 2 * SP * NC + base);
    float4 oa, ob;
    oa.x = w0*(float)p0[0] + w1*(float)p1[0] + w2*(float)p2[0];
    oa.y = w0*(float)p0[1] + w1*(float)p1[1] + w2*(float)p2[1];
    oa.z = w0*(float)p0[2] + w1*(float)p1[2] + w2*(float)p2[2];
    oa.w = w0*(float)p0[3] + w1*(float)p1[3] + w2*(float)p2[3];
    ob.x = w0*(float)p0[4] + w1*(float)p1[4] + w2*(float)p2[4];
    ob.y = w0*(float)p0[5] + w1*(float)p1[5] + w2*(float)p2[5];
    ob.z = w0*(float)p0[6] + w1*(float)p1[6] + w2*(float)p2[6];
    ob.w = w0*(float)p0[7] + w1*(float)p1[7] + w2*(float)p2[7];
    *(float4*)(Opre + base)     = oa;
    *(float4*)(Opre + base + 4) = ob;
}

// ---------------- K4: groupnorm stats ----------------
__global__ __launch_bounds__(256) void k_gnstats(const float* __restrict__ Opre,
                                                 float* __restrict__ stats)
{
    const int b = blockIdx.x, g = blockIdx.y;
    const int tid = threadIdx.x;
    const int coff = tid & 7, nb0 = tid >> 3;
    const float* base = Opre + (size_t)b * NS * NC + g * 8 + coff;
    float sum = 0.f, ss = 0.f;
#pragma unroll 4
    for (int k = 0; k < 128; ++k) {
        const float v = base[(size_t)(nb0 + 32 * k) * NC];
        sum += v; ss += v * v;
    }
    __shared__ float r1[256], r2[256];
    r1[tid] = sum; r2[tid] = ss;
    __syncthreads();
    for (int sft = 128; sft > 0; sft >>= 1) {
        if (tid < sft) { r1[tid] += r1[tid + sft]; r2[tid] += r2[tid + sft]; }
        __syncthreads();
    }
    if (tid == 0) {
        const float mean = r1[0] * (1.f / 32768.f);
        const float var  = r2[0] * (1.f / 32768.f) - mean * mean;
        stats[(b * NG + g) * 2 + 0] = mean;
        stats[(b * NG + g) * 2 + 1] = rsqrtf(var + GEPS);
    }
}

// ---------------- K5: apply GN + residual, [b][n][c] -> [b][c][n] ----------
__global__ __launch_bounds__(256) void k_gnapply(const float* __restrict__ Opre,
    const float* __restrict__ Hand, const float* __restrict__ gnw,
    const float* __restrict__ gnb, const float* __restrict__ stats,
    float* __restrict__ out)
{
    const int nt = blockIdx.x, ct = blockIdx.y, b = blockIdx.z;
    __shared__ float buf[64 * 65];
    const int tid = threadIdx.x;
    {
        const int nr = tid >> 4, c4 = (tid & 15) * 4;
#pragma unroll
        for (int k = 0; k < 4; ++k) {
            const int n = nr + 16 * k;
            const float4 v = *(const float4*)(Opre + ((size_t)b * NS + nt * 64 + n) * NC
                                              + ct * 64 + c4);
            buf[n * 65 + c4 + 0] = v.x; buf[n * 65 + c4 + 1] = v.y;
            buf[n * 65 + c4 + 2] = v.z; buf[n * 65 + c4 + 3] = v.w;
        }
    }
    __syncthreads();
    const int nw = tid & 63, c0 = tid >> 6;
#pragma unroll
    for (int k = 0; k < 16; ++k) {
        const int cl = c0 + 4 * k;
        const int c  = ct * 64 + cl;
        const int g  = c >> 3;
        const float mean = stats[(b * NG + g) * 2 + 0];
        const float rstd = stats[(b * NG + g) * 2 + 1];
        const size_t oidx = ((size_t)b * NC + c) * NS + nt * 64 + nw;
        out[oidx] = (buf[nw * 65 + cl] - mean) * rstd * gnw[c] + gnb[c] + Hand[oidx];
    }
}

extern "C" void kernel_launch(void* const* d_in, const int* in_sizes, int n_in,
                              void* d_out, int out_size, void* d_ws, size_t ws_size,
                              hipStream_t stream)
{
    const float* Hand = (const float*)d_in[0];
    const float* U    = (const float*)d_in[1];
    const float* WHw  = (const float*)d_in[2];
    const float* WHb  = (const float*)d_in[3];
    const float* WUw  = (const float*)d_in[4];
    const float* WUb  = (const float*)d_in[5];
    const float* gnw  = (const float*)d_in[6];
    const float* gnb  = (const float*)d_in[7];
    float* out = (float*)d_out;

    // workspace (~48.6 MiB). Opre(fp32,16Mi) ALIASES qT+kTsw (dead post-attn).
    char* ws = (char*)d_ws;
    _Float16* qT    = (_Float16*)(ws);                  //  8 MiB  [b][n][c]
    _Float16* kTsw  = (_Float16*)(ws + 8388608);        //  8 MiB  swizzled tiles
    _Float16* Uh    = (_Float16*)(ws + 16777216);       //  8 MiB  [b][c][m]
    _Float16* Wh16  = (_Float16*)(ws + 25165824);       //  128 KiB
    _Float16* Wu16  = (_Float16*)(ws + 25296896);       //  128 KiB
    float*    mstat = (float*)(ws + 25427968);          //  192 KiB [3][b][n]
    float*    lstat = (float*)(ws + 25624576);          //  192 KiB
    float*    stats = (float*)(ws + 25821184);          //  1 KiB
    _Float16* Ppart = (_Float16*)(ws + 25822208);       //  24 MiB [3][b][n][c]
    float*    Opre  = (float*)(ws);                     //  16 MiB alias

    k_convert<<<dim3((NB * NC * NS) / 256), 256, 0, stream>>>(U, WHw, WUw, Uh, Wh16, Wu16);
    k_qkgemm <<<dim3(64, NB, 2), 256, 0, stream>>>(Hand, U, Wh16, Wu16, WHb, WUb, qT, kTsw);
    k_attn   <<<dim3(NB, 64, NSPLIT), 256, 0, stream>>>(qT, kTsw, Uh, Ppart, mstat, lstat);
    k_merge  <<<dim3(NS / 8, NB), 256, 0, stream>>>(Ppart, mstat, lstat, Opre);
    k_gnstats<<<dim3(NB, NG), 256, 0, stream>>>(Opre, stats);
    k_gnapply<<<dim3(64, 4, NB), 256, 0, stream>>>(Opre, Hand, gnw, gnb, stats, out);
}

// Round 4
// 329.489 us; speedup vs baseline: 1.7016x; 1.3210x over previous
//
#include <hip/hip_runtime.h>
#include <hip/hip_fp16.h>
#include <math.h>

// CrossFeatureAffinityPooling on gfx950 — R4 (R3 + parity fix + end-drain)
// k_attn: m-tile 32, double-buffered K DMA, raw-barrier software pipeline
// (fine-grained vmcnt, no full drains), U->VGPR prefetch, NT partial stores.

typedef _Float16 v8h __attribute__((ext_vector_type(8)));
typedef float    v4f __attribute__((ext_vector_type(4)));

#define NB 4
#define NC 256
#define NS 4096
#define NG 32
#define GEPS 1e-5f
#define NSPLIT 3

// raw barrier: LDS-visibility only (lgkm drain), vmem stays in flight
#define ASYNC_BARRIER() asm volatile("s_waitcnt lgkmcnt(0)\n\ts_barrier" ::: "memory")

// kTsw layout: 32-row tiles (16 KB), halfword offset within tile:
//   (m&31)*256 + (((c>>3) ^ (m&7)) * 8) + (c&7)   -> identity DMA, conflict-free reads

// ---------------- K0: convert U and weights to fp16 ----------------
__global__ __launch_bounds__(256) void k_convert(const float* __restrict__ U,
    const float* __restrict__ Wh, const float* __restrict__ Wu,
    _Float16* __restrict__ Uh, _Float16* __restrict__ Wh16, _Float16* __restrict__ Wu16)
{
    const int i = blockIdx.x * 256 + threadIdx.x;
    Uh[i] = (_Float16)U[i];
    if (i < NC * NC) { Wh16[i] = (_Float16)Wh[i]; Wu16[i] = (_Float16)Wu[i]; }
}

// ---------------- K1: q^T / k^T GEMM ----------------
__global__ __launch_bounds__(256) void k_qkgemm(const float* __restrict__ Hand,
    const float* __restrict__ U, const _Float16* __restrict__ Wh16,
    const _Float16* __restrict__ Wu16, const float* __restrict__ WHb,
    const float* __restrict__ WUb, _Float16* __restrict__ qT, _Float16* __restrict__ kTsw)
{
    const int nt = blockIdx.x, b = blockIdx.y, z = blockIdx.z;
    const float*    X    = z ? U    : Hand;
    const _Float16* W    = z ? Wu16 : Wh16;
    const float*    bias = z ? WUb  : WHb;

    const int tid = threadIdx.x, w = tid >> 6, lane = tid & 63;
    const int q4 = lane >> 4, l15 = lane & 15;
    const int n = nt * 64 + w * 16 + l15;

    const float* Xcol = X + (size_t)b * NC * NS + n;
    v8h A[8];
#pragma unroll
    for (int kc = 0; kc < 8; ++kc) {
        const int c0 = kc * 32 + q4 * 8;
        v8h a;
#pragma unroll
        for (int j = 0; j < 8; ++j) a[j] = (_Float16)Xcol[(size_t)(c0 + j) * NS];
        A[kc] = a;
    }

#pragma unroll 4
    for (int osub = 0; osub < 16; ++osub) {
        const int o = osub * 16 + l15;
        const _Float16* Wrow = W + (size_t)o * NC;
        v4f acc = {0.f, 0.f, 0.f, 0.f};
#pragma unroll
        for (int kc = 0; kc < 8; ++kc) {
            const v8h bf = *(const v8h*)(Wrow + kc * 32 + q4 * 8);
            acc = __builtin_amdgcn_mfma_f32_16x16x32_f16(A[kc], bf, acc, 0, 0, 0);
        }
        const float bv = bias[o];
        if (z == 0) {
            _Float16* orow = qT + ((size_t)b * NS + nt * 64 + w * 16 + q4 * 4) * NC + o;
#pragma unroll
            for (int r = 0; r < 4; ++r) orow[(size_t)r * NC] = (_Float16)(acc[r] + bv);
        } else {
            _Float16* kb = kTsw + (size_t)b * 128 * 8192;
#pragma unroll
            for (int r = 0; r < 4; ++r) {
                const int m = nt * 64 + w * 16 + q4 * 4 + r;
                kb[(size_t)(m >> 5) * 8192 + (m & 31) * 256
                   + (((o >> 3) ^ (m & 7)) * 8) + (o & 7)] = (_Float16)(acc[r] + bv);
            }
        }
    }
}

// ---------------- K2: flash attention partial, software-pipelined ----------
__global__ __launch_bounds__(256, 3) void k_attn(const _Float16* __restrict__ qT,
    const _Float16* __restrict__ kTsw, const _Float16* __restrict__ Uh,
    _Float16* __restrict__ Ppart, float* __restrict__ mstat, float* __restrict__ lstat)
{
    const int b  = blockIdx.x;
    const int nt = blockIdx.y;
    const int s  = blockIdx.z;
    const int t0 = (s == 0) ? 0 : (s == 1 ? 43 : 86);
    const int t1 = (s == 2) ? 128 : t0 + 43;

    __shared__ __align__(16) _Float16 Klds[2][32 * 256];   // 2 x 16 KB
    __shared__ __align__(16) _Float16 Plds[64 * 32];       // 4 KB
    __shared__ float alphaS[64];

    const int tid = threadIdx.x, w = tid >> 6, lane = tid & 63;
    const int q4 = lane >> 4, l15 = lane & 15;

    const _Float16* kTb = kTsw + (size_t)b * 128 * 8192;
    const _Float16* Uhb = Uh + (size_t)b * NC * NS;

    // prologue: DMA K[t0] -> buf (t0&1)  [parity must match in-loop p = t&1]
    {
        const _Float16* src = kTb + (size_t)t0 * 8192;
#pragma unroll
        for (int j = 0; j < 4; ++j) {
            const int ch = w * 4 + j;
            __builtin_amdgcn_global_load_lds(
                (const __attribute__((address_space(1))) void*)(src + ch * 512 + lane * 8),
                (__attribute__((address_space(3))) void*)(&Klds[t0 & 1][ch * 512]), 16, 0, 0);
        }
    }

    v8h Q[8];
    {
        const _Float16* qrow = qT + ((size_t)b * NS + nt * 64 + w * 16 + l15) * NC;
#pragma unroll
        for (int kc = 0; kc < 8; ++kc) Q[kc] = *(const v8h*)(qrow + kc * 32 + q4 * 8);
    }

    v4f O[4][4];
#pragma unroll
    for (int i = 0; i < 4; ++i)
#pragma unroll
        for (int j = 0; j < 4; ++j) O[i][j] = (v4f){0.f, 0.f, 0.f, 0.f};
    float mi[4] = {-INFINITY, -INFINITY, -INFINITY, -INFINITY};
    float li[4] = {0.f, 0.f, 0.f, 0.f};

    for (int t = t0; t < t1; ++t) {
        const int p = t & 1;
        const int m0 = t * 32;

        // ---- U[t] prefetch to VGPRs (PV operand this iter) ----
        v8h Ur[4];
#pragma unroll
        for (int js = 0; js < 4; ++js)
            Ur[js] = *(const v8h*)(Uhb + (size_t)(w * 64 + js * 16 + l15) * NS + m0 + q4 * 8);
        asm volatile("" ::: "memory");   // pin U-before-DMA issue order (vmcnt math)

        // ---- DMA K[t+1] into other buffer (full-iteration flight time).
        // Last iter wraps to t0: keeps per-wave outstanding-count uniform so
        // vmcnt(8) below still retires DMA(t); drained once after the loop. ----
        {
            const int tn = (t + 1 < t1) ? t + 1 : t0;
            const _Float16* src = kTb + (size_t)tn * 8192;
#pragma unroll
            for (int j = 0; j < 4; ++j) {
                const int ch = w * 4 + j;
                __builtin_amdgcn_global_load_lds(
                    (const __attribute__((address_space(1))) void*)(src + ch * 512 + lane * 8),
                    (__attribute__((address_space(3))) void*)(&Klds[p ^ 1][ch * 512]), 16, 0, 0);
            }
        }

        // per-wave outstanding: DMA(t)=4 oldest, U(t)=4, DMA(t+1)=4 -> retire DMA(t) only
        asm volatile("s_waitcnt vmcnt(8)" ::: "memory");
        ASYNC_BARRIER();   // all waves' K[t] resident; PV(t-1)/P-reads done

        // ---- QK^T: 16 n-rows x 32 m per wave ----
        v4f sv[2];
        sv[0] = (v4f){0.f, 0.f, 0.f, 0.f};
        sv[1] = (v4f){0.f, 0.f, 0.f, 0.f};
#pragma unroll
        for (int kc = 0; kc < 8; ++kc) {
#pragma unroll
            for (int ms = 0; ms < 2; ++ms) {
                const v8h kf = *(const v8h*)(&Klds[p][(ms * 16 + l15) * 256
                                             + (((kc * 4 + q4) ^ (l15 & 7)) * 8)]);
                sv[ms] = __builtin_amdgcn_mfma_f32_16x16x32_f16(Q[kc], kf, sv[ms], 0, 0, 0);
            }
        }

        // ---- online softmax over 32 cols ----
        float al[4];
#pragma unroll
        for (int r = 0; r < 4; ++r) {
            float tm = fmaxf(sv[0][r], sv[1][r]);
#pragma unroll
            for (int off = 1; off < 16; off <<= 1) tm = fmaxf(tm, __shfl_xor(tm, off, 64));
            const float mn = fmaxf(mi[r], tm);
            al[r] = __expf(mi[r] - mn);
            mi[r] = mn;
            float sum = 0.f;
#pragma unroll
            for (int ms = 0; ms < 2; ++ms) {
                const float pe = __expf(sv[ms][r] - mn);
                sv[ms][r] = pe; sum += pe;
            }
#pragma unroll
            for (int off = 1; off < 16; off <<= 1) sum += __shfl_xor(sum, off, 64);
            li[r] = li[r] * al[r] + sum;
        }
        if (l15 == 0) {
#pragma unroll
            for (int r = 0; r < 4; ++r) alphaS[w * 16 + q4 * 4 + r] = al[r];
        }
        // P -> LDS, swizzle chunk' = (col>>3) ^ ((row>>2)&3)
#pragma unroll
        for (int ms = 0; ms < 2; ++ms)
#pragma unroll
            for (int r = 0; r < 4; ++r) {
                const int row = w * 16 + q4 * 4 + r;
                const int col = ms * 16 + l15;
                Plds[row * 32 + (((col >> 3) ^ ((row >> 2) & 3)) * 8) + (col & 7)]
                    = (_Float16)sv[ms][r];
            }
        ASYNC_BARRIER();   // P/alpha visible; K[t] reads retired (lgkm drained)

        // ---- O = O*alpha + P x U ----
#pragma unroll
        for (int is = 0; is < 4; ++is) {
            v4f aa;
#pragma unroll
            for (int r = 0; r < 4; ++r) aa[r] = alphaS[is * 16 + q4 * 4 + r];
#pragma unroll
            for (int js = 0; js < 4; ++js) O[is][js] *= aa;
        }
#pragma unroll
        for (int is = 0; is < 4; ++is) {
            const v8h Pf = *(const v8h*)(&Plds[(is * 16 + l15) * 32
                                         + ((q4 ^ ((l15 >> 2) & 3)) * 8)]);
#pragma unroll
            for (int js = 0; js < 4; ++js)
                O[is][js] = __builtin_amdgcn_mfma_f32_16x16x32_f16(Pf, Ur[js], O[is][js], 0, 0, 0);
        }
    }

    // drain the wrap DMA before s_endpgm: an in-flight global_load_lds landing
    // after this workgroup's LDS is reassigned would corrupt another block.
    asm volatile("s_waitcnt vmcnt(0)" ::: "memory");

    // ---- epilogue: raw partial O (fp16, nontemporal) + per-row m,l ----
    if (l15 == 0) {
#pragma unroll
        for (int r = 0; r < 4; ++r) {
            const int n = nt * 64 + w * 16 + q4 * 4 + r;
            mstat[(size_t)(s * NB + b) * NS + n] = mi[r];
            lstat[(size_t)(s * NB + b) * NS + n] = li[r];
        }
    }
#pragma unroll
    for (int is = 0; is < 4; ++is)
#pragma unroll
        for (int js = 0; js < 4; ++js)
#pragma unroll
            for (int r = 0; r < 4; ++r) {
                _Float16* dst = Ppart + ((size_t)(s * NB + b) * NS + nt * 64 + is * 16
                                         + q4 * 4 + r) * NC + w * 64 + js * 16 + l15;
                __builtin_nontemporal_store((_Float16)O[is][js][r], dst);
            }
}

// ---------------- K3: flash-decoding merge of 3 partials -> fp32 Opre ------
__global__ __launch_bounds__(256) void k_merge(const _Float16* __restrict__ Pp,
    const float* __restrict__ mstat, const float* __restrict__ lstat,
    float* __restrict__ Opre)
{
    const int b = blockIdx.y, tid = threadIdx.x;
    const int n = blockIdx.x * 8 + (tid >> 5);
    const int c0 = (tid & 31) * 8;
    const size_t nb = (size_t)b * NS + n;
    const size_t SP = (size_t)NB * NS;
    const float m0 = mstat[nb], m1 = mstat[SP + nb], m2 = mstat[2 * SP + nb];
    const float l0 = lstat[nb], l1 = lstat[SP + nb], l2 = lstat[2 * SP + nb];
    const float M  = fmaxf(m0, fmaxf(m1, m2));
    const float e0 = __expf(m0 - M), e1 = __expf(m1 - M), e2 = __expf(m2 - M);
    const float inv = 1.f / (e0 * l0 + e1 * l1 + e2 * l2);
    const float w0 = e0 * inv, w1 = e1 * inv, w2 = e2 * inv;
    const size_t base = nb * NC + c0;
    const v8h p0 = *(const v8h*)(Pp + base);
    const v8h p1 = *(const v8h*)(Pp + SP * NC + base);
    const v8h p2 = *(const v8h*)(Pp + 2 * SP * NC + base);
    float4 oa, ob;
    oa.x = w0*(float)p0[0] + w1*(float)p1[0] + w2*(float)p2[0];
    oa.y = w0*(float)p0[1] + w1*(float)p1[1] + w2*(float)p2[1];
    oa.z = w0*(float)p0[2] + w1*(float)p1[2] + w2*(float)p2[2];
    oa.w = w0*(float)p0[3] + w1*(float)p1[3] + w2*(float)p2[3];
    ob.x = w0*(float)p0[4] + w1*(float)p1[4] + w2*(float)p2[4];
    ob.y = w0*(float)p0[5] + w1*(float)p1[5] + w2*(float)p2[5];
    ob.z = w0*(float)p0[6] + w1*(float)p1[6] + w2*(float)p2[6];
    ob.w = w0*(float)p0[7] + w1*(float)p1[7] + w2*(float)p2[7];
    *(float4*)(Opre + base)     = oa;
    *(float4*)(Opre + base + 4) = ob;
}

// ---------------- K4: groupnorm stats ----------------
__global__ __launch_bounds__(256) void k_gnstats(const float* __restrict__ Opre,
                                                 float* __restrict__ stats)
{
    const int b = blockIdx.x, g = blockIdx.y;
    const int tid = threadIdx.x;
    const int coff = tid & 7, nb0 = tid >> 3;
    const float* base = Opre + (size_t)b * NS * NC + g * 8 + coff;
    float sum = 0.f, ss = 0.f;
#pragma unroll 4
    for (int k = 0; k < 128; ++k) {
        const float v = base[(size_t)(nb0 + 32 * k) * NC];
        sum += v; ss += v * v;
    }
    __shared__ float r1[256], r2[256];
    r1[tid] = sum; r2[tid] = ss;
    __syncthreads();
    for (int sft = 128; sft > 0; sft >>= 1) {
        if (tid < sft) { r1[tid] += r1[tid + sft]; r2[tid] += r2[tid + sft]; }
        __syncthreads();
    }
    if (tid == 0) {
        const float mean = r1[0] * (1.f / 32768.f);
        const float var  = r2[0] * (1.f / 32768.f) - mean * mean;
        stats[(b * NG + g) * 2 + 0] = mean;
        stats[(b * NG + g) * 2 + 1] = rsqrtf(var + GEPS);
    }
}

// ---------------- K5: apply GN + residual, [b][n][c] -> [b][c][n] ----------
__global__ __launch_bounds__(256) void k_gnapply(const float* __restrict__ Opre,
    const float* __restrict__ Hand, const float* __restrict__ gnw,
    const float* __restrict__ gnb, const float* __restrict__ stats,
    float* __restrict__ out)
{
    const int nt = blockIdx.x, ct = blockIdx.y, b = blockIdx.z;
    __shared__ float buf[64 * 65];
    const int tid = threadIdx.x;
    {
        const int nr = tid >> 4, c4 = (tid & 15) * 4;
#pragma unroll
        for (int k = 0; k < 4; ++k) {
            const int n = nr + 16 * k;
            const float4 v = *(const float4*)(Opre + ((size_t)b * NS + nt * 64 + n) * NC
                                              + ct * 64 + c4);
            buf[n * 65 + c4 + 0] = v.x; buf[n * 65 + c4 + 1] = v.y;
            buf[n * 65 + c4 + 2] = v.z; buf[n * 65 + c4 + 3] = v.w;
        }
    }
    __syncthreads();
    const int nw = tid & 63, c0 = tid >> 6;
#pragma unroll
    for (int k = 0; k < 16; ++k) {
        const int cl = c0 + 4 * k;
        const int c  = ct * 64 + cl;
        const int g  = c >> 3;
        const float mean = stats[(b * NG + g) * 2 + 0];
        const float rstd = stats[(b * NG + g) * 2 + 1];
        const size_t oidx = ((size_t)b * NC + c) * NS + nt * 64 + nw;
        out[oidx] = (buf[nw * 65 + cl] - mean) * rstd * gnw[c] + gnb[c] + Hand[oidx];
    }
}

extern "C" void kernel_launch(void* const* d_in, const int* in_sizes, int n_in,
                              void* d_out, int out_size, void* d_ws, size_t ws_size,
                              hipStream_t stream)
{
    const float* Hand = (const float*)d_in[0];
    const float* U    = (const float*)d_in[1];
    const float* WHw  = (const float*)d_in[2];
    const float* WHb  = (const float*)d_in[3];
    const float* WUw  = (const float*)d_in[4];
    const float* WUb  = (const float*)d_in[5];
    const float* gnw  = (const float*)d_in[6];
    const float* gnb  = (const float*)d_in[7];
    float* out = (float*)d_out;

    // workspace (~49.7 MiB). Opre(fp32,16Mi) ALIASES qT/kTsw (dead post-attn).
    char* ws = (char*)d_ws;
    _Float16* qT    = (_Float16*)(ws);                  //  8 MiB  [b][n][c]
    _Float16* kTsw  = (_Float16*)(ws + 8388608);        //  8 MiB  swizzled 32-row tiles
    _Float16* Uh    = (_Float16*)(ws + 16777216);       //  8 MiB  [b][c][m]
    _Float16* Wh16  = (_Float16*)(ws + 25165824);       //  128 KiB
    _Float16* Wu16  = (_Float16*)(ws + 25296896);       //  128 KiB
    float*    mstat = (float*)(ws + 25427968);          //  192 KiB [3][b][n]
    float*    lstat = (float*)(ws + 25624576);          //  192 KiB
    float*    stats = (float*)(ws + 25821184);          //  1 KiB
    _Float16* Ppart = (_Float16*)(ws + 25822208);       //  24 MiB [3][b][n][c]
    float*    Opre  = (float*)(ws);                     //  16 MiB alias

    k_convert<<<dim3((NB * NC * NS) / 256), 256, 0, stream>>>(U, WHw, WUw, Uh, Wh16, Wu16);
    k_qkgemm <<<dim3(64, NB, 2), 256, 0, stream>>>(Hand, U, Wh16, Wu16, WHb, WUb, qT, kTsw);
    k_attn   <<<dim3(NB, 64, NSPLIT), 256, 0, stream>>>(qT, kTsw, Uh, Ppart, mstat, lstat);
    k_merge  <<<dim3(NS / 8, NB), 256, 0, stream>>>(Ppart, mstat, lstat, Opre);
    k_gnstats<<<dim3(NB, NG), 256, 0, stream>>>(Opre, stats);
    k_gnapply<<<dim3(64, 4, NB), 256, 0, stream>>>(Opre, Hand, gnw, gnb, stats, out);
}

// Round 5
// 276.799 us; speedup vs baseline: 2.0255x; 1.1904x over previous
//
#include <hip/hip_runtime.h>
#include <hip/hip_fp16.h>
#include <math.h>

// CrossFeatureAffinityPooling on gfx950 — R5
// R4 + (a) softmax reductions moved off the LDS pipe onto VALU via DPP row_ror,
// (b) lane-local deferred li (no per-iter sum reduce), (c) alphaS b128 reads,
// (d) W pre-swizzled for coalesced qkgemm frag loads, (e) gnstats fused into
// k_merge via atomics (removes one 16 MB pass).

typedef _Float16 v8h __attribute__((ext_vector_type(8)));
typedef float    v4f __attribute__((ext_vector_type(4)));

#define NB 4
#define NC 256
#define NS 4096
#define NG 32
#define GEPS 1e-5f
#define NSPLIT 3

// raw barrier: LDS-visibility only (lgkm drain), vmem stays in flight
#define ASYNC_BARRIER() asm volatile("s_waitcnt lgkmcnt(0)\n\ts_barrier" ::: "memory")

// DPP rotation-reduce within each 16-lane row (= the l15 domain of MFMA quads).
// ROW_ROR:n dpp_ctrl = 0x120 | n.
template <int CTRL>
__device__ __forceinline__ float dpp_rot(float x) {
    int r = __builtin_amdgcn_update_dpp(__float_as_int(x), __float_as_int(x),
                                        CTRL, 0xF, 0xF, false);
    return __int_as_float(r);
}
__device__ __forceinline__ float row_max16(float x) {
    x = fmaxf(x, dpp_rot<0x128>(x));
    x = fmaxf(x, dpp_rot<0x124>(x));
    x = fmaxf(x, dpp_rot<0x122>(x));
    x = fmaxf(x, dpp_rot<0x121>(x));
    return x;
}
__device__ __forceinline__ float row_sum16(float x) {
    x = x + dpp_rot<0x128>(x);
    x = x + dpp_rot<0x124>(x);
    x = x + dpp_rot<0x122>(x);
    x = x + dpp_rot<0x121>(x);
    return x;
}

// ---------------- K0: convert U + weights (weights into MFMA-frag order) ----
// Wsw index for (o,c): frag (osub=o>>4, kc=c>>5) is 1 KB read by lane=q4*16+l15
// as 8 contiguous halves: idx = ((osub*8+kc)*64 + (c>>3&3)*16 + (o&15))*8 + (c&7)
__global__ __launch_bounds__(256) void k_convert(const float* __restrict__ U,
    const float* __restrict__ Wh, const float* __restrict__ Wu,
    _Float16* __restrict__ Uh, _Float16* __restrict__ Wh16, _Float16* __restrict__ Wu16)
{
    const int i = blockIdx.x * 256 + threadIdx.x;
    Uh[i] = (_Float16)U[i];
    if (i < NC * NC) {
        const int o = i >> 8, c = i & 255;
        const int idx = ((((o >> 4) * 8 + (c >> 5)) * 4 + ((c >> 3) & 3)) * 16
                         + (o & 15)) * 8 + (c & 7);
        Wh16[idx] = (_Float16)Wh[i];
        Wu16[idx] = (_Float16)Wu[i];
    }
}

// ---------------- K1: q^T / k^T GEMM ----------------
__global__ __launch_bounds__(256) void k_qkgemm(const float* __restrict__ Hand,
    const float* __restrict__ U, const _Float16* __restrict__ Wh16,
    const _Float16* __restrict__ Wu16, const float* __restrict__ WHb,
    const float* __restrict__ WUb, _Float16* __restrict__ qT, _Float16* __restrict__ kTsw)
{
    const int nt = blockIdx.x, b = blockIdx.y, z = blockIdx.z;
    const float*    X    = z ? U    : Hand;
    const _Float16* W    = z ? Wu16 : Wh16;
    const float*    bias = z ? WUb  : WHb;

    const int tid = threadIdx.x, w = tid >> 6, lane = tid & 63;
    const int q4 = lane >> 4, l15 = lane & 15;
    const int n = nt * 64 + w * 16 + l15;

    const float* Xcol = X + (size_t)b * NC * NS + n;
    v8h A[8];
#pragma unroll
    for (int kc = 0; kc < 8; ++kc) {
        const int c0 = kc * 32 + q4 * 8;
        v8h a;
#pragma unroll
        for (int j = 0; j < 8; ++j) a[j] = (_Float16)Xcol[(size_t)(c0 + j) * NS];
        A[kc] = a;
    }

#pragma unroll 4
    for (int osub = 0; osub < 16; ++osub) {
        const int o = osub * 16 + l15;
        v4f acc = {0.f, 0.f, 0.f, 0.f};
#pragma unroll
        for (int kc = 0; kc < 8; ++kc) {
            // pre-swizzled: wave reads 1 KB contiguous, lane-coalesced b128
            const v8h bf = *(const v8h*)(W + ((size_t)(osub * 8 + kc) * 64 + lane) * 8);
            acc = __builtin_amdgcn_mfma_f32_16x16x32_f16(A[kc], bf, acc, 0, 0, 0);
        }
        const float bv = bias[o];
        if (z == 0) {
            _Float16* orow = qT + ((size_t)b * NS + nt * 64 + w * 16 + q4 * 4) * NC + o;
#pragma unroll
            for (int r = 0; r < 4; ++r) orow[(size_t)r * NC] = (_Float16)(acc[r] + bv);
        } else {
            _Float16* kb = kTsw + (size_t)b * 128 * 8192;
#pragma unroll
            for (int r = 0; r < 4; ++r) {
                const int m = nt * 64 + w * 16 + q4 * 4 + r;
                kb[(size_t)(m >> 5) * 8192 + (m & 31) * 256
                   + (((o >> 3) ^ (m & 7)) * 8) + (o & 7)] = (_Float16)(acc[r] + bv);
            }
        }
    }
}

// ---------------- K2: flash attention partial, software-pipelined ----------
__global__ __launch_bounds__(256, 3) void k_attn(const _Float16* __restrict__ qT,
    const _Float16* __restrict__ kTsw, const _Float16* __restrict__ Uh,
    _Float16* __restrict__ Ppart, float* __restrict__ mstat, float* __restrict__ lstat)
{
    const int b  = blockIdx.x;
    const int nt = blockIdx.y;
    const int s  = blockIdx.z;
    const int t0 = (s == 0) ? 0 : (s == 1 ? 43 : 86);
    const int t1 = (s == 2) ? 128 : t0 + 43;

    __shared__ __align__(16) _Float16 Klds[2][32 * 256];   // 2 x 16 KB
    __shared__ __align__(16) _Float16 Plds[64 * 32];       // 4 KB
    __shared__ __align__(16) float alphaS[64];

    const int tid = threadIdx.x, w = tid >> 6, lane = tid & 63;
    const int q4 = lane >> 4, l15 = lane & 15;

    const _Float16* kTb = kTsw + (size_t)b * 128 * 8192;
    const _Float16* Uhb = Uh + (size_t)b * NC * NS;

    // prologue: DMA K[t0] -> buf (t0&1)  [parity matches in-loop p = t&1]
    {
        const _Float16* src = kTb + (size_t)t0 * 8192;
#pragma unroll
        for (int j = 0; j < 4; ++j) {
            const int ch = w * 4 + j;
            __builtin_amdgcn_global_load_lds(
                (const __attribute__((address_space(1))) void*)(src + ch * 512 + lane * 8),
                (__attribute__((address_space(3))) void*)(&Klds[t0 & 1][ch * 512]), 16, 0, 0);
        }
    }

    v8h Q[8];
    {
        const _Float16* qrow = qT + ((size_t)b * NS + nt * 64 + w * 16 + l15) * NC;
#pragma unroll
        for (int kc = 0; kc < 8; ++kc) Q[kc] = *(const v8h*)(qrow + kc * 32 + q4 * 8);
    }

    v4f O[4][4];
#pragma unroll
    for (int i = 0; i < 4; ++i)
#pragma unroll
        for (int j = 0; j < 4; ++j) O[i][j] = (v4f){0.f, 0.f, 0.f, 0.f};
    float mi[4] = {-INFINITY, -INFINITY, -INFINITY, -INFINITY};
    float li[4] = {0.f, 0.f, 0.f, 0.f};   // lane-local partial (own cols only)

    for (int t = t0; t < t1; ++t) {
        const int p = t & 1;
        const int m0 = t * 32;

        // ---- U[t] prefetch to VGPRs ----
        v8h Ur[4];
#pragma unroll
        for (int js = 0; js < 4; ++js)
            Ur[js] = *(const v8h*)(Uhb + (size_t)(w * 64 + js * 16 + l15) * NS + m0 + q4 * 8);
        asm volatile("" ::: "memory");   // pin U-before-DMA issue order (vmcnt math)

        // ---- DMA K[t+1] into other buffer; last iter wraps (uniform counts) ----
        {
            const int tn = (t + 1 < t1) ? t + 1 : t0;
            const _Float16* src = kTb + (size_t)tn * 8192;
#pragma unroll
            for (int j = 0; j < 4; ++j) {
                const int ch = w * 4 + j;
                __builtin_amdgcn_global_load_lds(
                    (const __attribute__((address_space(1))) void*)(src + ch * 512 + lane * 8),
                    (__attribute__((address_space(3))) void*)(&Klds[p ^ 1][ch * 512]), 16, 0, 0);
            }
        }

        // outstanding: DMA(t)=4 oldest, U(t)=4, DMA(t+1)=4 -> retire DMA(t) only
        asm volatile("s_waitcnt vmcnt(8)" ::: "memory");
        ASYNC_BARRIER();   // K[t] resident for all; Plds consumed by all

        // ---- QK^T: 16 n-rows x 32 m per wave ----
        v4f sv[2];
        sv[0] = (v4f){0.f, 0.f, 0.f, 0.f};
        sv[1] = (v4f){0.f, 0.f, 0.f, 0.f};
#pragma unroll
        for (int kc = 0; kc < 8; ++kc) {
#pragma unroll
            for (int ms = 0; ms < 2; ++ms) {
                const v8h kf = *(const v8h*)(&Klds[p][(ms * 16 + l15) * 256
                                             + (((kc * 4 + q4) ^ (l15 & 7)) * 8)]);
                sv[ms] = __builtin_amdgcn_mfma_f32_16x16x32_f16(Q[kc], kf, sv[ms], 0, 0, 0);
            }
        }

        // ---- online softmax: DPP max (VALU pipe), lane-local li ----
        float al[4];
#pragma unroll
        for (int r = 0; r < 4; ++r) {
            const float tm = row_max16(fmaxf(sv[0][r], sv[1][r]));
            const float mn = fmaxf(mi[r], tm);
            al[r] = __expf(mi[r] - mn);
            mi[r] = mn;
            const float p0 = __expf(sv[0][r] - mn);
            const float p1 = __expf(sv[1][r] - mn);
            sv[0][r] = p0; sv[1][r] = p1;
            li[r] = li[r] * al[r] + p0 + p1;   // own 2 cols; reduced after loop
        }
        if (l15 == 0) {
#pragma unroll
            for (int r = 0; r < 4; ++r) alphaS[w * 16 + q4 * 4 + r] = al[r];
        }
        // P -> LDS fp16, swizzle chunk' = (col>>3) ^ ((row>>2)&3)
#pragma unroll
        for (int ms = 0; ms < 2; ++ms)
#pragma unroll
            for (int r = 0; r < 4; ++r) {
                const int row = w * 16 + q4 * 4 + r;
                const int col = ms * 16 + l15;
                Plds[row * 32 + (((col >> 3) ^ ((row >> 2) & 3)) * 8) + (col & 7)]
                    = (_Float16)sv[ms][r];
            }
        ASYNC_BARRIER();   // P/alpha visible; K[t] reads retired

        // ---- O = O*alpha + P x U ----
#pragma unroll
        for (int is = 0; is < 4; ++is) {
            const float4 av = *(const float4*)&alphaS[is * 16 + q4 * 4];
            const v4f aa = {av.x, av.y, av.z, av.w};
#pragma unroll
            for (int js = 0; js < 4; ++js) O[is][js] *= aa;
        }
#pragma unroll
        for (int is = 0; is < 4; ++is) {
            const v8h Pf = *(const v8h*)(&Plds[(is * 16 + l15) * 32
                                         + ((q4 ^ ((l15 >> 2) & 3)) * 8)]);
#pragma unroll
            for (int js = 0; js < 4; ++js)
                O[is][js] = __builtin_amdgcn_mfma_f32_16x16x32_f16(Pf, Ur[js], O[is][js], 0, 0, 0);
        }
    }

    // drain wrap DMA before LDS could be reassigned at s_endpgm
    asm volatile("s_waitcnt vmcnt(0)" ::: "memory");

    // ---- epilogue: reduce li across the quad-row, write stats + raw O ----
#pragma unroll
    for (int r = 0; r < 4; ++r) li[r] = row_sum16(li[r]);
    if (l15 == 0) {
#pragma unroll
        for (int r = 0; r < 4; ++r) {
            const int n = nt * 64 + w * 16 + q4 * 4 + r;
            mstat[(size_t)(s * NB + b) * NS + n] = mi[r];
            lstat[(size_t)(s * NB + b) * NS + n] = li[r];
        }
    }
#pragma unroll
    for (int is = 0; is < 4; ++is)
#pragma unroll
        for (int js = 0; js < 4; ++js)
#pragma unroll
            for (int r = 0; r < 4; ++r) {
                _Float16* dst = Ppart + ((size_t)(s * NB + b) * NS + nt * 64 + is * 16
                                         + q4 * 4 + r) * NC + w * 64 + js * 16 + l15;
                __builtin_nontemporal_store((_Float16)O[is][js][r], dst);
            }
}

// ---------------- K3: merge 3 partials -> fp32 Opre + fused GN partial sums
__global__ __launch_bounds__(256) void k_merge(const _Float16* __restrict__ Pp,
    const float* __restrict__ mstat, const float* __restrict__ lstat,
    float* __restrict__ Opre, float* __restrict__ statacc)
{
    const int b = blockIdx.y, tid = threadIdx.x;
    const int n = blockIdx.x * 8 + (tid >> 5);
    const int c0 = (tid & 31) * 8;            // == group (tid&31) exactly
    const size_t nb = (size_t)b * NS + n;
    const size_t SP = (size_t)NB * NS;
    const float m0 = mstat[nb], m1 = mstat[SP + nb], m2 = mstat[2 * SP + nb];
    const float l0 = lstat[nb], l1 = lstat[SP + nb], l2 = lstat[2 * SP + nb];
    const float M  = fmaxf(m0, fmaxf(m1, m2));
    const float e0 = __expf(m0 - M), e1 = __expf(m1 - M), e2 = __expf(m2 - M);
    const float inv = 1.f / (e0 * l0 + e1 * l1 + e2 * l2);
    const float w0 = e0 * inv, w1 = e1 * inv, w2 = e2 * inv;
    const size_t base = nb * NC + c0;
    const v8h p0 = *(const v8h*)(Pp + base);
    const v8h p1 = *(const v8h*)(Pp + SP * NC + base);
    const v8h p2 = *(const v8h*)(Pp + 2 * SP * NC + base);
    float v[8];
    float s1 = 0.f, s2 = 0.f;
#pragma unroll
    for (int j = 0; j < 8; ++j) {
        v[j] = w0 * (float)p0[j] + w1 * (float)p1[j] + w2 * (float)p2[j];
        s1 += v[j]; s2 += v[j] * v[j];
    }
    *(float4*)(Opre + base)     = make_float4(v[0], v[1], v[2], v[3]);
    *(float4*)(Opre + base + 4) = make_float4(v[4], v[5], v[6], v[7]);

    // fused groupnorm partial sums: thread's 8 c-values lie in one group
    __shared__ float r1[256], r2[256];
    r1[tid] = s1; r2[tid] = s2;
    __syncthreads();
    if (tid < 32) {
        float a = 0.f, q = 0.f;
#pragma unroll
        for (int k = 0; k < 8; ++k) { a += r1[tid + 32 * k]; q += r2[tid + 32 * k]; }
        atomicAdd(&statacc[(b * NG + tid) * 2 + 0], a);
        atomicAdd(&statacc[(b * NG + tid) * 2 + 1], q);
    }
}

// ---------------- K4: apply GN + residual, [b][n][c] -> [b][c][n] ----------
__global__ __launch_bounds__(256) void k_gnapply(const float* __restrict__ Opre,
    const float* __restrict__ Hand, const float* __restrict__ gnw,
    const float* __restrict__ gnb, const float* __restrict__ statacc,
    float* __restrict__ out)
{
    const int nt = blockIdx.x, ct = blockIdx.y, b = blockIdx.z;
    __shared__ float buf[64 * 65];
    const int tid = threadIdx.x;
    {
        const int nr = tid >> 4, c4 = (tid & 15) * 4;
#pragma unroll
        for (int k = 0; k < 4; ++k) {
            const int n = nr + 16 * k;
            const float4 v = *(const float4*)(Opre + ((size_t)b * NS + nt * 64 + n) * NC
                                              + ct * 64 + c4);
            buf[n * 65 + c4 + 0] = v.x; buf[n * 65 + c4 + 1] = v.y;
            buf[n * 65 + c4 + 2] = v.z; buf[n * 65 + c4 + 3] = v.w;
        }
    }
    __syncthreads();
    const int nw = tid & 63, c0 = tid >> 6;
#pragma unroll
    for (int k = 0; k < 16; ++k) {
        const int cl = c0 + 4 * k;
        const int c  = ct * 64 + cl;
        const int g  = c >> 3;
        const float s1   = statacc[(b * NG + g) * 2 + 0];
        const float s2   = statacc[(b * NG + g) * 2 + 1];
        const float mean = s1 * (1.f / 32768.f);
        const float var  = s2 * (1.f / 32768.f) - mean * mean;
        const float rstd = rsqrtf(var + GEPS);
        const size_t oidx = ((size_t)b * NC + c) * NS + nt * 64 + nw;
        out[oidx] = (buf[nw * 65 + cl] - mean) * rstd * gnw[c] + gnb[c] + Hand[oidx];
    }
}

extern "C" void kernel_launch(void* const* d_in, const int* in_sizes, int n_in,
                              void* d_out, int out_size, void* d_ws, size_t ws_size,
                              hipStream_t stream)
{
    const float* Hand = (const float*)d_in[0];
    const float* U    = (const float*)d_in[1];
    const float* WHw  = (const float*)d_in[2];
    const float* WHb  = (const float*)d_in[3];
    const float* WUw  = (const float*)d_in[4];
    const float* WUb  = (const float*)d_in[5];
    const float* gnw  = (const float*)d_in[6];
    const float* gnb  = (const float*)d_in[7];
    float* out = (float*)d_out;

    // workspace (~49.7 MiB). Opre(fp32,16Mi) ALIASES qT/kTsw (dead post-attn).
    char* ws = (char*)d_ws;
    _Float16* qT     = (_Float16*)(ws);                  //  8 MiB  [b][n][c]
    _Float16* kTsw   = (_Float16*)(ws + 8388608);        //  8 MiB  swizzled 32-row tiles
    _Float16* Uh     = (_Float16*)(ws + 16777216);       //  8 MiB  [b][c][m]
    _Float16* Wh16   = (_Float16*)(ws + 25165824);       //  128 KiB (frag-order)
    _Float16* Wu16   = (_Float16*)(ws + 25296896);       //  128 KiB (frag-order)
    float*    mstat  = (float*)(ws + 25427968);          //  192 KiB [3][b][n]
    float*    lstat  = (float*)(ws + 25624576);          //  192 KiB
    float*    statacc= (float*)(ws + 25821184);          //  2 KiB [b][g][2]
    _Float16* Ppart  = (_Float16*)(ws + 25823232);       //  24 MiB [3][b][n][c]
    float*    Opre   = (float*)(ws);                     //  16 MiB alias

    hipMemsetAsync(statacc, 0, NB * NG * 2 * sizeof(float), stream);
    k_convert<<<dim3((NB * NC * NS) / 256), 256, 0, stream>>>(U, WHw, WUw, Uh, Wh16, Wu16);
    k_qkgemm <<<dim3(64, NB, 2), 256, 0, stream>>>(Hand, U, Wh16, Wu16, WHb, WUb, qT, kTsw);
    k_attn   <<<dim3(NB, 64, NSPLIT), 256, 0, stream>>>(qT, kTsw, Uh, Ppart, mstat, lstat);
    k_merge  <<<dim3(NS / 8, NB), 256, 0, stream>>>(Ppart, mstat, lstat, Opre, statacc);
    k_gnapply<<<dim3(64, 4, NB), 256, 0, stream>>>(Opre, Hand, gnw, gnb, statacc, out);
}

// Round 6
// 276.128 us; speedup vs baseline: 2.0304x; 1.0024x over previous
//
#include <hip/hip_runtime.h>
#include <hip/hip_fp16.h>
#include <math.h>

// CrossFeatureAffinityPooling on gfx950 — R6
// R5 + bank-conflict fix via PADDED STRIDES (no XOR): kT row stride 272 halves
// (544 B = +8 dwords/row bank rotation), Plds stride 40 halves (80 B).
// Uh production fused into k_qkgemm (z=1 writes its A-frags); k_convert = W only.

typedef _Float16 v8h __attribute__((ext_vector_type(8)));
typedef float    v4f __attribute__((ext_vector_type(4)));

#define NB 4
#define NC 256
#define NS 4096
#define NG 32
#define GEPS 1e-5f
#define NSPLIT 3
#define KSTRIDE 272            // halves per K-tile row (256 data + 16 pad)
#define KTILE   8704           // halves per 32-row K tile (17408 B = 17 KiB)
#define PSTRIDE 40             // halves per P row (32 data + 8 pad)

// raw barrier: LDS-visibility only (lgkm drain), vmem stays in flight
#define ASYNC_BARRIER() asm volatile("s_waitcnt lgkmcnt(0)\n\ts_barrier" ::: "memory")

// DPP rotation-reduce within each 16-lane row (the l15 domain of MFMA quads)
template <int CTRL>
__device__ __forceinline__ float dpp_rot(float x) {
    int r = __builtin_amdgcn_update_dpp(__float_as_int(x), __float_as_int(x),
                                        CTRL, 0xF, 0xF, false);
    return __int_as_float(r);
}
__device__ __forceinline__ float row_max16(float x) {
    x = fmaxf(x, dpp_rot<0x128>(x));
    x = fmaxf(x, dpp_rot<0x124>(x));
    x = fmaxf(x, dpp_rot<0x122>(x));
    x = fmaxf(x, dpp_rot<0x121>(x));
    return x;
}
__device__ __forceinline__ float row_sum16(float x) {
    x = x + dpp_rot<0x128>(x);
    x = x + dpp_rot<0x124>(x);
    x = x + dpp_rot<0x122>(x);
    x = x + dpp_rot<0x121>(x);
    return x;
}

// ---------------- K0: convert weights into MFMA-frag order (W only) --------
__global__ __launch_bounds__(256) void k_convert(const float* __restrict__ Wh,
    const float* __restrict__ Wu, _Float16* __restrict__ Wh16, _Float16* __restrict__ Wu16)
{
    const int i = blockIdx.x * 256 + threadIdx.x;   // i < NC*NC
    const int o = i >> 8, c = i & 255;
    const int idx = ((((o >> 4) * 8 + (c >> 5)) * 4 + ((c >> 3) & 3)) * 16
                     + (o & 15)) * 8 + (c & 7);
    Wh16[idx] = (_Float16)Wh[i];
    Wu16[idx] = (_Float16)Wu[i];
}

// ---------------- K1: q^T / k^T GEMM (+ fused Uh materialization) ----------
__global__ __launch_bounds__(256) void k_qkgemm(const float* __restrict__ Hand,
    const float* __restrict__ U, const _Float16* __restrict__ Wh16,
    const _Float16* __restrict__ Wu16, const float* __restrict__ WHb,
    const float* __restrict__ WUb, _Float16* __restrict__ qT,
    _Float16* __restrict__ kTsw, _Float16* __restrict__ Uh)
{
    const int nt = blockIdx.x, b = blockIdx.y, z = blockIdx.z;
    const float*    X    = z ? U    : Hand;
    const _Float16* W    = z ? Wu16 : Wh16;
    const float*    bias = z ? WUb  : WHb;

    const int tid = threadIdx.x, w = tid >> 6, lane = tid & 63;
    const int q4 = lane >> 4, l15 = lane & 15;
    const int n = nt * 64 + w * 16 + l15;

    const float* Xcol = X + (size_t)b * NC * NS + n;
    v8h A[8];
#pragma unroll
    for (int kc = 0; kc < 8; ++kc) {
        const int c0 = kc * 32 + q4 * 8;
        v8h a;
#pragma unroll
        for (int j = 0; j < 8; ++j) a[j] = (_Float16)Xcol[(size_t)(c0 + j) * NS];
        A[kc] = a;
    }

    // fused: z=1 blocks hold U^T[n][c] fp16 frags -> write Uh[b][c][n]
    if (z == 1) {
        _Float16* ub = Uh + (size_t)b * NC * NS + n;
#pragma unroll
        for (int kc = 0; kc < 8; ++kc) {
            const int c0 = kc * 32 + q4 * 8;
#pragma unroll
            for (int j = 0; j < 8; ++j) ub[(size_t)(c0 + j) * NS] = A[kc][j];
        }
    }

#pragma unroll 4
    for (int osub = 0; osub < 16; ++osub) {
        const int o = osub * 16 + l15;
        v4f acc = {0.f, 0.f, 0.f, 0.f};
#pragma unroll
        for (int kc = 0; kc < 8; ++kc) {
            // pre-swizzled W: wave reads 1 KB contiguous, lane-coalesced b128
            const v8h bf = *(const v8h*)(W + ((size_t)(osub * 8 + kc) * 64 + lane) * 8);
            acc = __builtin_amdgcn_mfma_f32_16x16x32_f16(A[kc], bf, acc, 0, 0, 0);
        }
        const float bv = bias[o];
        if (z == 0) {
            _Float16* orow = qT + ((size_t)b * NS + nt * 64 + w * 16 + q4 * 4) * NC + o;
#pragma unroll
            for (int r = 0; r < 4; ++r) orow[(size_t)r * NC] = (_Float16)(acc[r] + bv);
        } else {
            _Float16* kb = kTsw + (size_t)b * 128 * KTILE;
#pragma unroll
            for (int r = 0; r < 4; ++r) {
                const int m = nt * 64 + w * 16 + q4 * 4 + r;
                kb[(size_t)(m >> 5) * KTILE + (m & 31) * KSTRIDE + o] = (_Float16)(acc[r] + bv);
            }
        }
    }
}

// ---------------- K2: flash attention partial, software-pipelined ----------
__global__ __launch_bounds__(256, 3) void k_attn(const _Float16* __restrict__ qT,
    const _Float16* __restrict__ kTsw, const _Float16* __restrict__ Uh,
    _Float16* __restrict__ Ppart, float* __restrict__ mstat, float* __restrict__ lstat)
{
    const int b  = blockIdx.x;
    const int nt = blockIdx.y;
    const int s  = blockIdx.z;
    const int t0 = (s == 0) ? 0 : (s == 1 ? 43 : 86);
    const int t1 = (s == 2) ? 128 : t0 + 43;

    __shared__ __align__(16) _Float16 Klds[2][KTILE];     // 2 x 17 KiB, padded rows
    __shared__ __align__(16) _Float16 Plds[64 * PSTRIDE]; // 5 KiB, padded rows
    __shared__ __align__(16) float alphaS[64];

    const int tid = threadIdx.x, w = tid >> 6, lane = tid & 63;
    const int q4 = lane >> 4, l15 = lane & 15;

    const _Float16* kTb = kTsw + (size_t)b * 128 * KTILE;
    const _Float16* Uhb = Uh + (size_t)b * NC * NS;

    // prologue: DMA K[t0] -> buf (t0&1). 17 chunks of 1 KiB; each wave copies 5
    // via (w*5+j) mod 17 (chunks 0..2 double-copied -> uniform per-wave vmcnt).
    {
        const _Float16* src = kTb + (size_t)t0 * KTILE;
#pragma unroll
        for (int j = 0; j < 5; ++j) {
            const int ch = (w * 5 + j) % 17;
            __builtin_amdgcn_global_load_lds(
                (const __attribute__((address_space(1))) void*)(src + ch * 512 + lane * 8),
                (__attribute__((address_space(3))) void*)(&Klds[t0 & 1][ch * 512]), 16, 0, 0);
        }
    }

    v8h Q[8];
    {
        const _Float16* qrow = qT + ((size_t)b * NS + nt * 64 + w * 16 + l15) * NC;
#pragma unroll
        for (int kc = 0; kc < 8; ++kc) Q[kc] = *(const v8h*)(qrow + kc * 32 + q4 * 8);
    }

    v4f O[4][4];
#pragma unroll
    for (int i = 0; i < 4; ++i)
#pragma unroll
        for (int j = 0; j < 4; ++j) O[i][j] = (v4f){0.f, 0.f, 0.f, 0.f};
    float mi[4] = {-INFINITY, -INFINITY, -INFINITY, -INFINITY};
    float li[4] = {0.f, 0.f, 0.f, 0.f};   // lane-local partial (own cols only)

    for (int t = t0; t < t1; ++t) {
        const int p = t & 1;
        const int m0 = t * 32;

        // ---- U[t] prefetch to VGPRs ----
        v8h Ur[4];
#pragma unroll
        for (int js = 0; js < 4; ++js)
            Ur[js] = *(const v8h*)(Uhb + (size_t)(w * 64 + js * 16 + l15) * NS + m0 + q4 * 8);
        asm volatile("" ::: "memory");   // pin U-before-DMA issue order (vmcnt math)

        // ---- DMA K[t+1] into other buffer; last iter wraps (uniform counts) ----
        {
            const int tn = (t + 1 < t1) ? t + 1 : t0;
            const _Float16* src = kTb + (size_t)tn * KTILE;
#pragma unroll
            for (int j = 0; j < 5; ++j) {
                const int ch = (w * 5 + j) % 17;
                __builtin_amdgcn_global_load_lds(
                    (const __attribute__((address_space(1))) void*)(src + ch * 512 + lane * 8),
                    (__attribute__((address_space(3))) void*)(&Klds[p ^ 1][ch * 512]), 16, 0, 0);
            }
        }

        // outstanding: DMA(t)=5 oldest, U(t)=4, DMA(t+1)=5 -> retire DMA(t) only
        asm volatile("s_waitcnt vmcnt(9)" ::: "memory");
        ASYNC_BARRIER();   // K[t] resident for all; Plds consumed by all

        // ---- QK^T: 16 n-rows x 32 m per wave; plain padded-row addressing ----
        v4f sv[2];
        sv[0] = (v4f){0.f, 0.f, 0.f, 0.f};
        sv[1] = (v4f){0.f, 0.f, 0.f, 0.f};
#pragma unroll
        for (int kc = 0; kc < 8; ++kc) {
#pragma unroll
            for (int ms = 0; ms < 2; ++ms) {
                const v8h kf = *(const v8h*)(&Klds[p][(ms * 16 + l15) * KSTRIDE
                                             + (kc * 4 + q4) * 8]);
                sv[ms] = __builtin_amdgcn_mfma_f32_16x16x32_f16(Q[kc], kf, sv[ms], 0, 0, 0);
            }
        }

        // ---- online softmax: DPP max (VALU pipe), lane-local li ----
        float al[4];
#pragma unroll
        for (int r = 0; r < 4; ++r) {
            const float tm = row_max16(fmaxf(sv[0][r], sv[1][r]));
            const float mn = fmaxf(mi[r], tm);
            al[r] = __expf(mi[r] - mn);
            mi[r] = mn;
            const float p0 = __expf(sv[0][r] - mn);
            const float p1 = __expf(sv[1][r] - mn);
            sv[0][r] = p0; sv[1][r] = p1;
            li[r] = li[r] * al[r] + p0 + p1;   // own 2 cols; reduced after loop
        }
        if (l15 == 0) {
#pragma unroll
            for (int r = 0; r < 4; ++r) alphaS[w * 16 + q4 * 4 + r] = al[r];
        }
        // P -> LDS fp16, plain padded rows (stride 40 halves)
#pragma unroll
        for (int ms = 0; ms < 2; ++ms)
#pragma unroll
            for (int r = 0; r < 4; ++r) {
                const int row = w * 16 + q4 * 4 + r;
                Plds[row * PSTRIDE + ms * 16 + l15] = (_Float16)sv[ms][r];
            }
        ASYNC_BARRIER();   // P/alpha visible; K[t] reads retired

        // ---- O = O*alpha + P x U ----
#pragma unroll
        for (int is = 0; is < 4; ++is) {
            const float4 av = *(const float4*)&alphaS[is * 16 + q4 * 4];
            const v4f aa = {av.x, av.y, av.z, av.w};
#pragma unroll
            for (int js = 0; js < 4; ++js) O[is][js] *= aa;
        }
#pragma unroll
        for (int is = 0; is < 4; ++is) {
            const v8h Pf = *(const v8h*)(&Plds[(is * 16 + l15) * PSTRIDE + q4 * 8]);
#pragma unroll
            for (int js = 0; js < 4; ++js)
                O[is][js] = __builtin_amdgcn_mfma_f32_16x16x32_f16(Pf, Ur[js], O[is][js], 0, 0, 0);
        }
    }

    // drain wrap DMA before LDS could be reassigned at s_endpgm
    asm volatile("s_waitcnt vmcnt(0)" ::: "memory");

    // ---- epilogue: reduce li across the quad-row, write stats + raw O ----
#pragma unroll
    for (int r = 0; r < 4; ++r) li[r] = row_sum16(li[r]);
    if (l15 == 0) {
#pragma unroll
        for (int r = 0; r < 4; ++r) {
            const int n = nt * 64 + w * 16 + q4 * 4 + r;
            mstat[(size_t)(s * NB + b) * NS + n] = mi[r];
            lstat[(size_t)(s * NB + b) * NS + n] = li[r];
        }
    }
#pragma unroll
    for (int is = 0; is < 4; ++is)
#pragma unroll
        for (int js = 0; js < 4; ++js)
#pragma unroll
            for (int r = 0; r < 4; ++r) {
                _Float16* dst = Ppart + ((size_t)(s * NB + b) * NS + nt * 64 + is * 16
                                         + q4 * 4 + r) * NC + w * 64 + js * 16 + l15;
                __builtin_nontemporal_store((_Float16)O[is][js][r], dst);
            }
}

// ---------------- K3: merge 3 partials -> fp32 Opre + fused GN partial sums
__global__ __launch_bounds__(256) void k_merge(const _Float16* __restrict__ Pp,
    const float* __restrict__ mstat, const float* __restrict__ lstat,
    float* __restrict__ Opre, float* __restrict__ statacc)
{
    const int b = blockIdx.y, tid = threadIdx.x;
    const int n = blockIdx.x * 8 + (tid >> 5);
    const int c0 = (tid & 31) * 8;            // == group (tid&31) exactly
    const size_t nb = (size_t)b * NS + n;
    const size_t SP = (size_t)NB * NS;
    const float m0 = mstat[nb], m1 = mstat[SP + nb], m2 = mstat[2 * SP + nb];
    const float l0 = lstat[nb], l1 = lstat[SP + nb], l2 = lstat[2 * SP + nb];
    const float M  = fmaxf(m0, fmaxf(m1, m2));
    const float e0 = __expf(m0 - M), e1 = __expf(m1 - M), e2 = __expf(m2 - M);
    const float inv = 1.f / (e0 * l0 + e1 * l1 + e2 * l2);
    const float w0 = e0 * inv, w1 = e1 * inv, w2 = e2 * inv;
    const size_t base = nb * NC + c0;
    const v8h p0 = *(const v8h*)(Pp + base);
    const v8h p1 = *(const v8h*)(Pp + SP * NC + base);
    const v8h p2 = *(const v8h*)(Pp + 2 * SP * NC + base);
    float v[8];
    float s1 = 0.f, s2 = 0.f;
#pragma unroll
    for (int j = 0; j < 8; ++j) {
        v[j] = w0 * (float)p0[j] + w1 * (float)p1[j] + w2 * (float)p2[j];
        s1 += v[j]; s2 += v[j] * v[j];
    }
    *(float4*)(Opre + base)     = make_float4(v[0], v[1], v[2], v[3]);
    *(float4*)(Opre + base + 4) = make_float4(v[4], v[5], v[6], v[7]);

    __shared__ float r1[256], r2[256];
    r1[tid] = s1; r2[tid] = s2;
    __syncthreads();
    if (tid < 32) {
        float a = 0.f, q = 0.f;
#pragma unroll
        for (int k = 0; k < 8; ++k) { a += r1[tid + 32 * k]; q += r2[tid + 32 * k]; }
        atomicAdd(&statacc[(b * NG + tid) * 2 + 0], a);
        atomicAdd(&statacc[(b * NG + tid) * 2 + 1], q);
    }
}

// ---------------- K4: apply GN + residual, [b][n][c] -> [b][c][n] ----------
__global__ __launch_bounds__(256) void k_gnapply(const float* __restrict__ Opre,
    const float* __restrict__ Hand, const float* __restrict__ gnw,
    const float* __restrict__ gnb, const float* __restrict__ statacc,
    float* __restrict__ out)
{
    const int nt = blockIdx.x, ct = blockIdx.y, b = blockIdx.z;
    __shared__ float buf[64 * 65];
    const int tid = threadIdx.x;
    {
        const int nr = tid >> 4, c4 = (tid & 15) * 4;
#pragma unroll
        for (int k = 0; k < 4; ++k) {
            const int n = nr + 16 * k;
            const float4 v = *(const float4*)(Opre + ((size_t)b * NS + nt * 64 + n) * NC
                                              + ct * 64 + c4);
            buf[n * 65 + c4 + 0] = v.x; buf[n * 65 + c4 + 1] = v.y;
            buf[n * 65 + c4 + 2] = v.z; buf[n * 65 + c4 + 3] = v.w;
        }
    }
    __syncthreads();
    const int nw = tid & 63, c0 = tid >> 6;
#pragma unroll
    for (int k = 0; k < 16; ++k) {
        const int cl = c0 + 4 * k;
        const int c  = ct * 64 + cl;
        const int g  = c >> 3;
        const float s1   = statacc[(b * NG + g) * 2 + 0];
        const float s2   = statacc[(b * NG + g) * 2 + 1];
        const float mean = s1 * (1.f / 32768.f);
        const float var  = s2 * (1.f / 32768.f) - mean * mean;
        const float rstd = rsqrtf(var + GEPS);
        const size_t oidx = ((size_t)b * NC + c) * NS + nt * 64 + nw;
        out[oidx] = (buf[nw * 65 + cl] - mean) * rstd * gnw[c] + gnb[c] + Hand[oidx];
    }
}

extern "C" void kernel_launch(void* const* d_in, const int* in_sizes, int n_in,
                              void* d_out, int out_size, void* d_ws, size_t ws_size,
                              hipStream_t stream)
{
    const float* Hand = (const float*)d_in[0];
    const float* U    = (const float*)d_in[1];
    const float* WHw  = (const float*)d_in[2];
    const float* WHb  = (const float*)d_in[3];
    const float* WUw  = (const float*)d_in[4];
    const float* WUb  = (const float*)d_in[5];
    const float* gnw  = (const float*)d_in[6];
    const float* gnb  = (const float*)d_in[7];
    float* out = (float*)d_out;

    // workspace (~49.1 MiB). Opre(fp32,16Mi) ALIASES qT + kTsw head (dead post-attn).
    char* ws = (char*)d_ws;
    _Float16* qT     = (_Float16*)(ws);                  //  8 MiB   [b][n][c]
    _Float16* kTsw   = (_Float16*)(ws + 8388608);        //  8.5 MiB padded 32-row tiles
    _Float16* Uh     = (_Float16*)(ws + 17301504);       //  8 MiB   [b][c][m]
    _Float16* Wh16   = (_Float16*)(ws + 25690112);       //  128 KiB (frag-order)
    _Float16* Wu16   = (_Float16*)(ws + 25821184);       //  128 KiB (frag-order)
    float*    mstat  = (float*)(ws + 25952256);          //  192 KiB [3][b][n]
    float*    lstat  = (float*)(ws + 26148864);          //  192 KiB
    float*    statacc= (float*)(ws + 26345472);          //  2 KiB [b][g][2]
    _Float16* Ppart  = (_Float16*)(ws + 26347520);       //  24 MiB [3][b][n][c]
    float*    Opre   = (float*)(ws);                     //  16 MiB alias

    hipMemsetAsync(statacc, 0, NB * NG * 2 * sizeof(float), stream);
    k_convert<<<dim3((NC * NC) / 256), 256, 0, stream>>>(WHw, WUw, Wh16, Wu16);
    k_qkgemm <<<dim3(64, NB, 2), 256, 0, stream>>>(Hand, U, Wh16, Wu16, WHb, WUb, qT, kTsw, Uh);
    k_attn   <<<dim3(NB, 64, NSPLIT), 256, 0, stream>>>(qT, kTsw, Uh, Ppart, mstat, lstat);
    k_merge  <<<dim3(NS / 8, NB), 256, 0, stream>>>(Ppart, mstat, lstat, Opre, statacc);
    k_gnapply<<<dim3(64, 4, NB), 256, 0, stream>>>(Opre, Hand, gnw, gnb, statacc, out);
}